// Round 9
// baseline (338.544 us; speedup 1.0000x reference)
//
#include <hip/hip_runtime.h>
#include <hip/hip_fp16.h>

#define NVOX 65536
#define KVOL 125
#define NPAIR 1048576
#define CAP 48            // fixed bin capacity; out_idx ~ Poisson(16), 8 sigma headroom
#define FILL_BLOCKS 2048
#define QKV_BLOCKS 768
#define GATH_BLOCKS 1280

__device__ __forceinline__ float rdlane(float v, int j) {
    return __int_as_float(__builtin_amdgcn_readlane(__float_as_int(v), j));
}

// ---------------------------------------------------------------------------
// fill: pairlist bins via cursor ticket atomics (+posnorm piggyback).
// 2048 blocks (8/CU) -> enough TLP to hide the load->atomic->store chain.
// ---------------------------------------------------------------------------
__global__ __launch_bounds__(256) void fill_kernel(
    const float* __restrict__ pos, const int* __restrict__ kq_map,
    __half* __restrict__ nposh, int* __restrict__ cursor,
    unsigned int* __restrict__ pairlist)
{
    const int tid  = threadIdx.x;
    const int lane = tid & 63;
    const int wid  = tid >> 6;
    if (blockIdx.x < KVOL && wid == 0) {
        const float pv = pos[blockIdx.x * 64 + lane];
        float s = pv * pv;
        #pragma unroll
        for (int m = 1; m <= 8; m <<= 1) s += __shfl_xor(s, m);
        nposh[blockIdx.x * 64 + lane] = __float2half(pv / fmaxf(sqrtf(s), 1e-12f));
    }
    const int gtid = blockIdx.x * 256 + tid;            // 0..524287
    const int p0 = gtid;
    const int p1 = gtid + 524288;
    const unsigned k0 = (unsigned)kq_map[p0];
    const unsigned k1 = (unsigned)kq_map[p1];
    const int o0 = kq_map[NPAIR + p0];
    const int o1 = kq_map[NPAIR + p1];
    const int r0 = atomicAdd(&cursor[o0], 1);
    const int r1 = atomicAdd(&cursor[o1], 1);
    const unsigned i0 = k0 / 125u, i1 = k1 / 125u;
    if (r0 < CAP) pairlist[(size_t)o0 * CAP + r0] = (i0 << 7) | (k0 - i0 * 125u);
    if (r1 < CAP) pairlist[(size_t)o1 * CAP + r1] = (i1 << 7) | (k1 - i1 * 125u);
}

// ---------------------------------------------------------------------------
// qkv projection + per-head L2 norm, fp16 outputs. 768 blocks = 3/CU
// (matches launch_bounds), W^T staged in LDS, x broadcast via readlane.
// ---------------------------------------------------------------------------
__global__ __launch_bounds__(256, 3) void qkv_kernel(
    const float* __restrict__ x,
    const float* __restrict__ Wq, const float* __restrict__ bq,
    const float* __restrict__ Wk, const float* __restrict__ bk,
    const float* __restrict__ Wv, const float* __restrict__ bv,
    __half* __restrict__ nqh, unsigned int* __restrict__ kv)
{
    __shared__ float wt[3 * 64 * 68];   // W^T per matrix: [m][c][j], stride 68
    const int tid  = threadIdx.x;
    const int lane = tid & 63;
    const int wid  = tid >> 6;

    for (int idx = tid; idx < 3 * 4096; idx += 256) {
        const int m = idx >> 12;
        const int r = idx & 4095;
        const int j = r >> 6;
        const int c = r & 63;
        const float wv = (m == 0 ? Wq : (m == 1 ? Wk : Wv))[j * 64 + c];
        wt[(m * 64 + c) * 68 + j] = wv;
    }
    __syncthreads();

    const float* wtm0 = &wt[(0   + lane) * 68];
    const float* wtm1 = &wt[(64  + lane) * 68];
    const float* wtm2 = &wt[(128 + lane) * 68];
    const float bqv = bq[lane], bkv = bk[lane], bvv = bv[lane];
    const int t  = lane & 3;
    const int s0 = (lane & ~3) | ((t & 1) << 1);
    const int gw = blockIdx.x * 4 + wid;       // 3072 waves

    for (int nb = gw * 4; nb < NVOX; nb += QKV_BLOCKS * 16) {
        float xv[4], aq[4], ak[4], av[4];
        #pragma unroll
        for (int v = 0; v < 4; ++v) {
            xv[v] = x[(size_t)(nb + v) * 64 + lane];
            aq[v] = bqv; ak[v] = bkv; av[v] = bvv;
        }
        #pragma unroll 4
        for (int jb = 0; jb < 16; ++jb) {
            const int j = jb * 4;
            const float4 w0 = *(const float4*)&wtm0[j];
            const float4 w1 = *(const float4*)&wtm1[j];
            const float4 w2 = *(const float4*)&wtm2[j];
            #pragma unroll
            for (int v = 0; v < 4; ++v) {
                const float xj0 = rdlane(xv[v], j + 0);
                const float xj1 = rdlane(xv[v], j + 1);
                const float xj2 = rdlane(xv[v], j + 2);
                const float xj3 = rdlane(xv[v], j + 3);
                aq[v] += xj0 * w0.x + xj1 * w0.y + xj2 * w0.z + xj3 * w0.w;
                ak[v] += xj0 * w1.x + xj1 * w1.y + xj2 * w1.z + xj3 * w1.w;
                av[v] += xj0 * w2.x + xj1 * w2.y + xj2 * w2.z + xj3 * w2.w;
            }
        }
        #pragma unroll
        for (int v = 0; v < 4; ++v) {
            float sq = aq[v] * aq[v];
            float sk = ak[v] * ak[v];
            #pragma unroll
            for (int m = 1; m <= 8; m <<= 1) {
                sq += __shfl_xor(sq, m);
                sk += __shfl_xor(sk, m);
            }
            const float inq = aq[v] / fmaxf(sqrtf(sq), 1e-12f);
            const float ink = ak[v] / fmaxf(sqrtf(sk), 1e-12f);
            nqh[(size_t)(nb + v) * 64 + lane] = __float2half(inq);
            const unsigned hk = __half_as_ushort(__float2half(ink));
            const unsigned hv = __half_as_ushort(__float2half(av[v]));
            const unsigned combo = hk | (hv << 16);
            const unsigned g0 = (unsigned)__shfl((int)combo, s0);
            const unsigned g1 = (unsigned)__shfl((int)combo, s0 + 1);
            const unsigned b0 = (t >= 2) ? (g0 >> 16) : (g0 & 0xffffu);
            const unsigned b1 = (t >= 2) ? (g1 >> 16) : (g1 & 0xffffu);
            kv[(size_t)(nb + v) * 64 + lane] = b0 | (b1 << 16);
        }
    }
}

// ---------------------------------------------------------------------------
// Gather + attention + Wo projection + residual. fp16 Wo in LDS -> 28 KB
// total -> 5 blocks/CU. 2-deep pipelined pair loop.
// ---------------------------------------------------------------------------
__device__ __forceinline__ void pair_accum(
    unsigned pk, const uint4& u, const __half* npos_s, int cc,
    const float4& a4, float4& ac)
{
    const int kidx = (int)(pk & 127u);
    const float2 k01 = __half22float2(*(const __half2*)&u.x);
    const float2 k23 = __half22float2(*(const __half2*)&u.y);
    const float2 v01 = __half22float2(*(const __half2*)&u.z);
    const float2 v23 = __half22float2(*(const __half2*)&u.w);
    const __half2* np = (const __half2*)&npos_s[kidx * 64 + cc];
    const float2 c01 = __half22float2(np[0]);
    const float2 c23 = __half22float2(np[1]);
    float pdot = a4.x * (k01.x + c01.x) + a4.y * (k01.y + c01.y)
               + a4.z * (k23.x + c23.x) + a4.w * (k23.y + c23.y);
    pdot += __shfl_xor(pdot, 1);
    pdot += __shfl_xor(pdot, 2);
    ac.x += pdot * v01.x; ac.y += pdot * v01.y;
    ac.z += pdot * v23.x; ac.w += pdot * v23.y;
}

__global__ __launch_bounds__(256, 5) void gather_out_kernel(
    const int* __restrict__ cursor, const unsigned int* __restrict__ pairlist,
    const __half* __restrict__ nqh, const unsigned int* __restrict__ kv,
    const __half* __restrict__ nposh,
    const float* __restrict__ Wo, const float* __restrict__ bo,
    const float* __restrict__ x, float* __restrict__ out)
{
    __shared__ __half wo_h[4096];       // 8 KB (fp16 Wo)
    __shared__ __half npos_s[8192];     // 16 KB
    __shared__ float ms[4][4][64];      // 4 KB
    const int tid = threadIdx.x;
    for (int i = tid; i < 4096; i += 256) wo_h[i] = __float2half(Wo[i]);
    for (int i = tid; i < 1000; i += 256) ((uint4*)npos_s)[i] = ((const uint4*)nposh)[i];
    __syncthreads();

    const int lane = tid & 63;
    const int wid  = tid >> 6;
    const int l    = lane & 15;
    const int pg   = lane >> 4;
    const int cc   = l * 4;
    const int gw   = blockIdx.x * 4 + wid;   // 5120 waves
    const float4 bo4 = *(const float4*)&bo[cc];

    for (int nb = gw * 4; nb < NVOX; nb += GATH_BLOCKS * 16) {
        // ---- pair phase: 4 voxels, register accumulation ----
        #pragma unroll
        for (int v = 0; v < 4; ++v) {
            const int n = nb + v;
            const uint2 qp = *(const uint2*)(nqh + (size_t)n * 64 + cc);
            const float2 q01 = __half22float2(*(const __half2*)&qp.x);
            const float2 q23 = __half22float2(*(const __half2*)&qp.y);
            const float4 a4 = make_float4(q01.x, q01.y, q23.x, q23.y);
            const int s = n * CAP;
            const int cnt = min(cursor[n], CAP);
            const int e = s + cnt;
            float4 acc = make_float4(0.f, 0.f, 0.f, 0.f);
            int p = s + pg;
            while (p + 4 < e) {        // 2 pairs in flight per slot
                const unsigned pk0 = pairlist[p];
                const unsigned pk1 = pairlist[p + 4];
                const uint4 u0 = *(const uint4*)(kv + (size_t)(pk0 >> 7) * 64 + cc);
                const uint4 u1 = *(const uint4*)(kv + (size_t)(pk1 >> 7) * 64 + cc);
                pair_accum(pk0, u0, npos_s, cc, a4, acc);
                pair_accum(pk1, u1, npos_s, cc, a4, acc);
                p += 8;
            }
            if (p < e) {
                const unsigned pk = pairlist[p];
                const uint4 u = *(const uint4*)(kv + (size_t)(pk >> 7) * 64 + cc);
                pair_accum(pk, u, npos_s, cc, a4, acc);
            }
            acc.x += __shfl_xor(acc.x, 16); acc.y += __shfl_xor(acc.y, 16);
            acc.z += __shfl_xor(acc.z, 16); acc.w += __shfl_xor(acc.w, 16);
            acc.x += __shfl_xor(acc.x, 32); acc.y += __shfl_xor(acc.y, 32);
            acc.z += __shfl_xor(acc.z, 32); acc.w += __shfl_xor(acc.w, 32);
            if (pg == 0) *(float4*)&ms[wid][v][cc] = acc;
        }
        __syncthreads();
        // ---- epilogue: out = msg @ Wo + bo + x  (j split across quarters) ----
        float4 o4[4];
        #pragma unroll
        for (int v = 0; v < 4; ++v) o4[v] = make_float4(0.f, 0.f, 0.f, 0.f);
        #pragma unroll
        for (int ib = 0; ib < 4; ++ib) {
            float4 mq[4];
            #pragma unroll
            for (int v = 0; v < 4; ++v)
                mq[v] = *(const float4*)&ms[wid][v][pg * 16 + ib * 4];
            #pragma unroll
            for (int tt = 0; tt < 4; ++tt) {
                const int j = pg * 16 + ib * 4 + tt;
                const __half2* wp = (const __half2*)&wo_h[j * 64 + cc];
                const float2 wa = __half22float2(wp[0]);
                const float2 wb = __half22float2(wp[1]);
                #pragma unroll
                for (int v = 0; v < 4; ++v) {
                    const float m = (tt == 0 ? mq[v].x : tt == 1 ? mq[v].y :
                                     tt == 2 ? mq[v].z : mq[v].w);
                    o4[v].x += m * wa.x; o4[v].y += m * wa.y;
                    o4[v].z += m * wb.x; o4[v].w += m * wb.y;
                }
            }
        }
        #pragma unroll
        for (int v = 0; v < 4; ++v) {
            o4[v].x += __shfl_xor(o4[v].x, 16); o4[v].y += __shfl_xor(o4[v].y, 16);
            o4[v].z += __shfl_xor(o4[v].z, 16); o4[v].w += __shfl_xor(o4[v].w, 16);
            o4[v].x += __shfl_xor(o4[v].x, 32); o4[v].y += __shfl_xor(o4[v].y, 32);
            o4[v].z += __shfl_xor(o4[v].z, 32); o4[v].w += __shfl_xor(o4[v].w, 32);
        }
        if (pg == 0) {
            #pragma unroll
            for (int v = 0; v < 4; ++v) {
                const float4 xr = *(const float4*)&x[(size_t)(nb + v) * 64 + cc];
                float4 r;
                r.x = o4[v].x + bo4.x + xr.x;
                r.y = o4[v].y + bo4.y + xr.y;
                r.z = o4[v].z + bo4.z + xr.z;
                r.w = o4[v].w + bo4.w + xr.w;
                *(float4*)&out[(size_t)(nb + v) * 64 + cc] = r;
            }
        }
        __syncthreads();
    }
}

// ---------------------------------------------------------------------------
extern "C" void kernel_launch(void* const* d_in, const int* in_sizes, int n_in,
                              void* d_out, int out_size, void* d_ws, size_t ws_size,
                              hipStream_t stream) {
    const float* x   = (const float*)d_in[0];
    const float* Wq  = (const float*)d_in[1];
    const float* bq  = (const float*)d_in[2];
    const float* Wk  = (const float*)d_in[3];
    const float* bk  = (const float*)d_in[4];
    const float* Wv  = (const float*)d_in[5];
    const float* bv  = (const float*)d_in[6];
    const float* Wo  = (const float*)d_in[7];
    const float* bo  = (const float*)d_in[8];
    const float* pos = (const float*)d_in[9];
    const int*   kq  = (const int*)d_in[10];

    char* w = (char*)d_ws;
    unsigned int* kv       = (unsigned int*)w; w += (size_t)NVOX * 64 * 4;    // 16 MB
    unsigned int* pairlist = (unsigned int*)w; w += (size_t)NVOX * CAP * 4;   // 12 MB
    __half*       nqh      = (__half*)w;       w += (size_t)NVOX * 64 * 2;    // 8 MB
    int*          cursor   = (int*)w;          w += (size_t)NVOX * 4;         // 256 KB
    __half*       nposh    = (__half*)w;       w += 16384;                    // 16 KB

    hipMemsetAsync(cursor, 0, (size_t)NVOX * sizeof(int), stream);
    fill_kernel<<<FILL_BLOCKS, 256, 0, stream>>>(pos, kq, nposh, cursor, pairlist);
    qkv_kernel<<<QKV_BLOCKS, 256, 0, stream>>>(x, Wq, bq, Wk, bk, Wv, bv, nqh, kv);
    gather_out_kernel<<<GATH_BLOCKS, 256, 0, stream>>>(cursor, pairlist, nqh, kv, nposh,
                                                       Wo, bo, x, (float*)d_out);
}

// Round 10
// 303.727 us; speedup vs baseline: 1.1146x; 1.1146x over previous
//
#include <hip/hip_runtime.h>
#include <hip/hip_fp16.h>

#define NVOX 65536
#define KVOL 125
#define NPAIR 1048576
#define CAP 48            // fixed bin capacity; out_idx ~ Poisson(16), 8 sigma headroom
#define FILL_BLOCKS 2048
#define QKV_BLOCKS 768
#define GATH_BLOCKS 1024

__device__ __forceinline__ float rdlane(float v, int j) {
    return __int_as_float(__builtin_amdgcn_readlane(__float_as_int(v), j));
}

// ---------------------------------------------------------------------------
// fill: pairlist bins via cursor ticket atomics (+posnorm piggyback).
// 2048 blocks (8/CU) for TLP on the load->atomic->store chains.
// ---------------------------------------------------------------------------
__global__ __launch_bounds__(256) void fill_kernel(
    const float* __restrict__ pos, const int* __restrict__ kq_map,
    __half* __restrict__ nposh, int* __restrict__ cursor,
    unsigned int* __restrict__ pairlist)
{
    const int tid  = threadIdx.x;
    const int lane = tid & 63;
    const int wid  = tid >> 6;
    if (blockIdx.x < KVOL && wid == 0) {
        const float pv = pos[blockIdx.x * 64 + lane];
        float s = pv * pv;
        #pragma unroll
        for (int m = 1; m <= 8; m <<= 1) s += __shfl_xor(s, m);
        nposh[blockIdx.x * 64 + lane] = __float2half(pv / fmaxf(sqrtf(s), 1e-12f));
    }
    const int gtid = blockIdx.x * 256 + tid;            // 0..524287
    const int p0 = gtid;
    const int p1 = gtid + 524288;
    const unsigned k0 = (unsigned)kq_map[p0];
    const unsigned k1 = (unsigned)kq_map[p1];
    const int o0 = kq_map[NPAIR + p0];
    const int o1 = kq_map[NPAIR + p1];
    const int r0 = atomicAdd(&cursor[o0], 1);
    const int r1 = atomicAdd(&cursor[o1], 1);
    const unsigned i0 = k0 / 125u, i1 = k1 / 125u;
    if (r0 < CAP) pairlist[(size_t)o0 * CAP + r0] = (i0 << 7) | (k0 - i0 * 125u);
    if (r1 < CAP) pairlist[(size_t)o1 * CAP + r1] = (i1 << 7) | (k1 - i1 * 125u);
}

// ---------------------------------------------------------------------------
// qkv projection + per-head L2 norm, fp16 outputs. W^T staged in LDS,
// x broadcast via readlane.
// ---------------------------------------------------------------------------
__global__ __launch_bounds__(256, 3) void qkv_kernel(
    const float* __restrict__ x,
    const float* __restrict__ Wq, const float* __restrict__ bq,
    const float* __restrict__ Wk, const float* __restrict__ bk,
    const float* __restrict__ Wv, const float* __restrict__ bv,
    __half* __restrict__ nqh, unsigned int* __restrict__ kv)
{
    __shared__ float wt[3 * 64 * 68];   // W^T per matrix: [m][c][j], stride 68
    const int tid  = threadIdx.x;
    const int lane = tid & 63;
    const int wid  = tid >> 6;

    for (int idx = tid; idx < 3 * 4096; idx += 256) {
        const int m = idx >> 12;
        const int r = idx & 4095;
        const int j = r >> 6;
        const int c = r & 63;
        const float wv = (m == 0 ? Wq : (m == 1 ? Wk : Wv))[j * 64 + c];
        wt[(m * 64 + c) * 68 + j] = wv;
    }
    __syncthreads();

    const float* wtm0 = &wt[(0   + lane) * 68];
    const float* wtm1 = &wt[(64  + lane) * 68];
    const float* wtm2 = &wt[(128 + lane) * 68];
    const float bqv = bq[lane], bkv = bk[lane], bvv = bv[lane];
    const int t  = lane & 3;
    const int s0 = (lane & ~3) | ((t & 1) << 1);
    const int gw = blockIdx.x * 4 + wid;       // 3072 waves

    for (int nb = gw * 4; nb < NVOX; nb += QKV_BLOCKS * 16) {
        float xv[4], aq[4], ak[4], av[4];
        #pragma unroll
        for (int v = 0; v < 4; ++v) {
            xv[v] = x[(size_t)(nb + v) * 64 + lane];
            aq[v] = bqv; ak[v] = bkv; av[v] = bvv;
        }
        #pragma unroll 4
        for (int jb = 0; jb < 16; ++jb) {
            const int j = jb * 4;
            const float4 w0 = *(const float4*)&wtm0[j];
            const float4 w1 = *(const float4*)&wtm1[j];
            const float4 w2 = *(const float4*)&wtm2[j];
            #pragma unroll
            for (int v = 0; v < 4; ++v) {
                const float xj0 = rdlane(xv[v], j + 0);
                const float xj1 = rdlane(xv[v], j + 1);
                const float xj2 = rdlane(xv[v], j + 2);
                const float xj3 = rdlane(xv[v], j + 3);
                aq[v] += xj0 * w0.x + xj1 * w0.y + xj2 * w0.z + xj3 * w0.w;
                ak[v] += xj0 * w1.x + xj1 * w1.y + xj2 * w1.z + xj3 * w1.w;
                av[v] += xj0 * w2.x + xj1 * w2.y + xj2 * w2.z + xj3 * w2.w;
            }
        }
        #pragma unroll
        for (int v = 0; v < 4; ++v) {
            float sq = aq[v] * aq[v];
            float sk = ak[v] * ak[v];
            #pragma unroll
            for (int m = 1; m <= 8; m <<= 1) {
                sq += __shfl_xor(sq, m);
                sk += __shfl_xor(sk, m);
            }
            const float inq = aq[v] / fmaxf(sqrtf(sq), 1e-12f);
            const float ink = ak[v] / fmaxf(sqrtf(sk), 1e-12f);
            nqh[(size_t)(nb + v) * 64 + lane] = __float2half(inq);
            const unsigned hk = __half_as_ushort(__float2half(ink));
            const unsigned hv = __half_as_ushort(__float2half(av[v]));
            const unsigned combo = hk | (hv << 16);
            const unsigned g0 = (unsigned)__shfl((int)combo, s0);
            const unsigned g1 = (unsigned)__shfl((int)combo, s0 + 1);
            const unsigned b0 = (t >= 2) ? (g0 >> 16) : (g0 & 0xffffu);
            const unsigned b1 = (t >= 2) ? (g1 >> 16) : (g1 & 0xffffu);
            kv[(size_t)(nb + v) * 64 + lane] = b0 | (b1 << 16);
        }
    }
}

// ---------------------------------------------------------------------------
// Gather + attention + Wo projection + residual — R8-proven configuration:
// fp32 Wo in LDS (36 KB), 4 blocks/CU, VGPR 64 (no spills), 2-deep pipeline.
// ---------------------------------------------------------------------------
__device__ __forceinline__ void pair_accum(
    unsigned pk, const uint4& u, const __half* npos_s, int cc,
    const float4& a4, float4& ac)
{
    const int kidx = (int)(pk & 127u);
    const float2 k01 = __half22float2(*(const __half2*)&u.x);
    const float2 k23 = __half22float2(*(const __half2*)&u.y);
    const float2 v01 = __half22float2(*(const __half2*)&u.z);
    const float2 v23 = __half22float2(*(const __half2*)&u.w);
    const __half2* np = (const __half2*)&npos_s[kidx * 64 + cc];
    const float2 c01 = __half22float2(np[0]);
    const float2 c23 = __half22float2(np[1]);
    float pdot = a4.x * (k01.x + c01.x) + a4.y * (k01.y + c01.y)
               + a4.z * (k23.x + c23.x) + a4.w * (k23.y + c23.y);
    pdot += __shfl_xor(pdot, 1);
    pdot += __shfl_xor(pdot, 2);
    ac.x += pdot * v01.x; ac.y += pdot * v01.y;
    ac.z += pdot * v23.x; ac.w += pdot * v23.y;
}

__global__ __launch_bounds__(256, 4) void gather_out_kernel(
    const int* __restrict__ cursor, const unsigned int* __restrict__ pairlist,
    const __half* __restrict__ nqh, const unsigned int* __restrict__ kv,
    const __half* __restrict__ nposh,
    const float* __restrict__ Wo, const float* __restrict__ bo,
    const float* __restrict__ x, float* __restrict__ out)
{
    __shared__ float wo_s[4096];
    __shared__ __half npos_s[8192];
    __shared__ float ms[4][4][64];
    const int tid = threadIdx.x;
    for (int i = tid; i < 1024; i += 256) ((float4*)wo_s)[i] = ((const float4*)Wo)[i];
    for (int i = tid; i < 1000; i += 256) ((uint4*)npos_s)[i] = ((const uint4*)nposh)[i];
    __syncthreads();

    const int lane = tid & 63;
    const int wid  = tid >> 6;
    const int l    = lane & 15;
    const int pg   = lane >> 4;
    const int cc   = l * 4;
    const int gw   = blockIdx.x * 4 + wid;   // 4096 waves
    const float4 bo4 = *(const float4*)&bo[cc];

    for (int nb = gw * 4; nb < NVOX; nb += GATH_BLOCKS * 16) {
        // ---- pair phase: 4 voxels, register accumulation ----
        #pragma unroll
        for (int v = 0; v < 4; ++v) {
            const int n = nb + v;
            const uint2 qp = *(const uint2*)(nqh + (size_t)n * 64 + cc);
            const float2 q01 = __half22float2(*(const __half2*)&qp.x);
            const float2 q23 = __half22float2(*(const __half2*)&qp.y);
            const float4 a4 = make_float4(q01.x, q01.y, q23.x, q23.y);
            const int s = n * CAP;
            const int cnt = min(cursor[n], CAP);
            const int e = s + cnt;
            float4 acc = make_float4(0.f, 0.f, 0.f, 0.f);
            int p = s + pg;
            while (p + 4 < e) {        // 2 pairs in flight per slot
                const unsigned pk0 = pairlist[p];
                const unsigned pk1 = pairlist[p + 4];
                const uint4 u0 = *(const uint4*)(kv + (size_t)(pk0 >> 7) * 64 + cc);
                const uint4 u1 = *(const uint4*)(kv + (size_t)(pk1 >> 7) * 64 + cc);
                pair_accum(pk0, u0, npos_s, cc, a4, acc);
                pair_accum(pk1, u1, npos_s, cc, a4, acc);
                p += 8;
            }
            if (p < e) {
                const unsigned pk = pairlist[p];
                const uint4 u = *(const uint4*)(kv + (size_t)(pk >> 7) * 64 + cc);
                pair_accum(pk, u, npos_s, cc, a4, acc);
            }
            acc.x += __shfl_xor(acc.x, 16); acc.y += __shfl_xor(acc.y, 16);
            acc.z += __shfl_xor(acc.z, 16); acc.w += __shfl_xor(acc.w, 16);
            acc.x += __shfl_xor(acc.x, 32); acc.y += __shfl_xor(acc.y, 32);
            acc.z += __shfl_xor(acc.z, 32); acc.w += __shfl_xor(acc.w, 32);
            if (pg == 0) *(float4*)&ms[wid][v][cc] = acc;
        }
        __syncthreads();
        // ---- epilogue: out = msg @ Wo + bo + x  (j split across quarters) ----
        float4 o4[4];
        #pragma unroll
        for (int v = 0; v < 4; ++v) o4[v] = make_float4(0.f, 0.f, 0.f, 0.f);
        #pragma unroll
        for (int ib = 0; ib < 4; ++ib) {
            float4 mq[4];
            #pragma unroll
            for (int v = 0; v < 4; ++v)
                mq[v] = *(const float4*)&ms[wid][v][pg * 16 + ib * 4];
            #pragma unroll
            for (int tt = 0; tt < 4; ++tt) {
                const int j = pg * 16 + ib * 4 + tt;
                const float4 w4 = *(const float4*)&wo_s[j * 64 + cc];
                #pragma unroll
                for (int v = 0; v < 4; ++v) {
                    const float m = (tt == 0 ? mq[v].x : tt == 1 ? mq[v].y :
                                     tt == 2 ? mq[v].z : mq[v].w);
                    o4[v].x += m * w4.x; o4[v].y += m * w4.y;
                    o4[v].z += m * w4.z; o4[v].w += m * w4.w;
                }
            }
        }
        #pragma unroll
        for (int v = 0; v < 4; ++v) {
            o4[v].x += __shfl_xor(o4[v].x, 16); o4[v].y += __shfl_xor(o4[v].y, 16);
            o4[v].z += __shfl_xor(o4[v].z, 16); o4[v].w += __shfl_xor(o4[v].w, 16);
            o4[v].x += __shfl_xor(o4[v].x, 32); o4[v].y += __shfl_xor(o4[v].y, 32);
            o4[v].z += __shfl_xor(o4[v].z, 32); o4[v].w += __shfl_xor(o4[v].w, 32);
        }
        if (pg == 0) {
            #pragma unroll
            for (int v = 0; v < 4; ++v) {
                const float4 xr = *(const float4*)&x[(size_t)(nb + v) * 64 + cc];
                float4 r;
                r.x = o4[v].x + bo4.x + xr.x;
                r.y = o4[v].y + bo4.y + xr.y;
                r.z = o4[v].z + bo4.z + xr.z;
                r.w = o4[v].w + bo4.w + xr.w;
                *(float4*)&out[(size_t)(nb + v) * 64 + cc] = r;
            }
        }
        __syncthreads();
    }
}

// ---------------------------------------------------------------------------
extern "C" void kernel_launch(void* const* d_in, const int* in_sizes, int n_in,
                              void* d_out, int out_size, void* d_ws, size_t ws_size,
                              hipStream_t stream) {
    const float* x   = (const float*)d_in[0];
    const float* Wq  = (const float*)d_in[1];
    const float* bq  = (const float*)d_in[2];
    const float* Wk  = (const float*)d_in[3];
    const float* bk  = (const float*)d_in[4];
    const float* Wv  = (const float*)d_in[5];
    const float* bv  = (const float*)d_in[6];
    const float* Wo  = (const float*)d_in[7];
    const float* bo  = (const float*)d_in[8];
    const float* pos = (const float*)d_in[9];
    const int*   kq  = (const int*)d_in[10];

    char* w = (char*)d_ws;
    unsigned int* kv       = (unsigned int*)w; w += (size_t)NVOX * 64 * 4;    // 16 MB
    unsigned int* pairlist = (unsigned int*)w; w += (size_t)NVOX * CAP * 4;   // 12 MB
    __half*       nqh      = (__half*)w;       w += (size_t)NVOX * 64 * 2;    // 8 MB
    int*          cursor   = (int*)w;          w += (size_t)NVOX * 4;         // 256 KB
    __half*       nposh    = (__half*)w;       w += 16384;                    // 16 KB

    hipMemsetAsync(cursor, 0, (size_t)NVOX * sizeof(int), stream);
    fill_kernel<<<FILL_BLOCKS, 256, 0, stream>>>(pos, kq, nposh, cursor, pairlist);
    qkv_kernel<<<QKV_BLOCKS, 256, 0, stream>>>(x, Wq, bq, Wk, bk, Wv, bv, nqh, kv);
    gather_out_kernel<<<GATH_BLOCKS, 256, 0, stream>>>(cursor, pairlist, nqh, kv, nposh,
                                                       Wo, bo, x, (float*)d_out);
}